// Round 10
// baseline (412.357 us; speedup 1.0000x reference)
//
#include <hip/hip_runtime.h>

#define IN_DIM   512
#define OUT_DIM  256
#define N_MID    1280
#define BATCH    16384
#define NT       256
#define XPAD     520      // fallback kernel x stride

// net8: 256 blocks x 256 threads (4 waves), 64 rows/block, 1 block/CU,
// 1 wave/SIMD -> ~512-reg unified budget. Wall = per-block chunk-chain
// latency (R8/R9). R10: take ew2/tri latency OFF the chain:
//   - bnx: apply B-frags for chunk j+1 register-prefetched during chunk j
//   - tri: distance-2 (triple-buffer) register prefetch in resolver (TPW=12)
//   - phase-1 B double-buffer
//   - gather2c: LDS row-staged, fully coalesced global reads

// ---- workspace layout (max geometry: ksteps=48, tpm=64, nch=32) ----
#define EW2_ELEMS ((size_t)48 * 64 * 64 * 8)               // bf16 elems
#define EW2_BYTES (EW2_ELEMS * 2)                          // 3,145,728
#define TRI_OFF   EW2_BYTES
#define TRI_BYTES ((size_t)32 * 1024 * 4)                  // 131,072
#define HDR_OFF   (TRI_OFF + TRI_BYTES)
#define CMAP_OFF  (HDR_OFF + 32)
#define OCOL_OFF  (CMAP_OFF + N_MID * 4)
#define BIASC_OFF (OCOL_OFF + N_MID * 4)
#define WS_NEED   (BIASC_OFF + N_MID * 4)

typedef __attribute__((ext_vector_type(8))) short  bfrag;
typedef __attribute__((ext_vector_type(4))) float  ffrag;

__device__ __forceinline__ unsigned short f2bf(float f) {
    unsigned int u = __float_as_uint(f);
    u += 0x7FFFu + ((u >> 16) & 1u);       // RNE
    return (unsigned short)(u >> 16);
}

// static component select from float4 (constant-folded post-unroll)
__device__ __forceinline__ float f4c(const float4& v, int k) {
    return (k == 0) ? v.x : (k == 1) ? v.y : (k == 2) ? v.z : v.w;
}

// ============================================================
// Setup A: compact existing columns (1 wave).
// hdr = {Mc, Mpad, unused, nch=Mpad/32, tpm=Mpad/16}
// Mpad in {768, 896, 1024} (even TPW: chunk may not straddle waves).
// ============================================================
__global__ void build_maps_kernel(const int* __restrict__ exist,
                                  const float* __restrict__ bias,
                                  int* __restrict__ hdr,
                                  int* __restrict__ cmap,
                                  int* __restrict__ ocol,
                                  float* __restrict__ biasc) {
    const int lane = threadIdx.x;   // 64
    int base = 0;
    for (int r = 0; r < N_MID / 64; ++r) {
        const int i = r * 64 + lane;
        const int e = exist[i];
        const unsigned long long m  = __ballot(e != 0);
        const unsigned long long lt = (lane == 0) ? 0ull : (~0ull >> (64 - lane));
        const int pos = base + __popcll(m & lt);
        if (e) {
            cmap[pos]  = i;
            ocol[pos]  = (i >= N_MID - OUT_DIM) ? (i - (N_MID - OUT_DIM)) : -1;
            biasc[pos] = bias[i];
        }
        base += __popcll(m);
    }
    for (int idx = base + lane; idx < N_MID; idx += 64) {
        cmap[idx] = 0; ocol[idx] = -1; biasc[idx] = 0.f;
    }
    if (lane == 0) {
        const int Mc = base;
        int Mpad;
        if (Mc <= 768) Mpad = 768;
        else if (Mc <= 896) Mpad = 896;
        else if (Mc <= 1024) Mpad = 1024;
        else Mpad = (Mc + 127) & ~127;     // v1 fallback territory
        hdr[0] = Mc; hdr[1] = Mpad; hdr[2] = 0;
        hdr[3] = Mpad / 32; hdr[4] = Mpad / 16;
    }
}

// ============================================================
// Setup B (coalesced): gather eff_w -> bf16 MFMA B-fragment-major.
// Block b: kstep = b>>2, q8 = b&3 (one k-octet = 8 source rows).
// Stage the 8 full rows (w*conn folded) into LDS with coalesced float4
// reads, then LDS-gather by cmap and write coalesced uint4.
// ew2[((kstep*tpm + gt)*64 + (q8*16+l15))*8 + jj] = W[s][cmap[c]]
// ============================================================
__global__ __launch_bounds__(NT)
void gather2c_kernel(const float* __restrict__ w, const int* __restrict__ conn,
                     const int* __restrict__ hdr, const int* __restrict__ cmap,
                     unsigned short* __restrict__ ew2) {
    const int Mc = hdr[0], nch = hdr[3], tpm = hdr[4];
    if (tpm > 64) return;                          // v1 fallback case
    const int kstep = blockIdx.x >> 2;
    const int q8    = blockIdx.x & 3;
    if (kstep >= 16 + nch) return;

    __shared__ float rb[8][N_MID];                 // 40,960 B
    const int t = threadIdx.x;

    // ---- stage 8 rows, coalesced ----
    for (int idx = t; idx < 8 * (N_MID / 4); idx += NT) {
        const int j  = idx / (N_MID / 4);
        const int c4 = idx % (N_MID / 4);
        int sr = -1;
        if (kstep < 16) {
            sr = kstep * 32 + q8 * 8 + j;          // input row, always valid
        } else {
            const int s2 = (kstep - 16) * 32 + q8 * 8 + j;
            if (s2 < Mc) sr = IN_DIM + cmap[s2];
        }
        float4 v = make_float4(0.f, 0.f, 0.f, 0.f);
        if (sr >= 0) {
            const size_t o = (size_t)sr * N_MID + c4 * 4;
            v = *(const float4*)(w + o);
            const int4 cc = *(const int4*)(conn + o);
            v.x *= (float)cc.x; v.y *= (float)cc.y;
            v.z *= (float)cc.z; v.w *= (float)cc.w;
        }
        *(float4*)&rb[j][c4 * 4] = v;
    }
    __syncthreads();

    // ---- gather + write ----
    for (int i = t; i < tpm * 16; i += NT) {
        const int gt = i >> 4, l15 = i & 15;
        const int c  = gt * 16 + l15;
        const int cm = (c < Mc) ? cmap[c] : 0;
        unsigned short vv[8];
#pragma unroll
        for (int jj = 0; jj < 8; ++jj) {
            float v = 0.f;
            if (c < Mc) {
                if (kstep < 16) {
                    v = rb[jj][cm];
                } else {
                    const int s2 = (kstep - 16) * 32 + q8 * 8 + jj;
                    if (s2 < c && (s2 >> 5) != (c >> 5))
                        v = rb[jj][cm];            // s2>=Mc rows are zeroed
                }
            }
            vv[jj] = f2bf(v);
        }
        *(uint4*)&ew2[((size_t)(kstep * tpm + gt) * 64 + (q8 * 16 + l15)) * 8] = *(uint4*)vv;
    }
}

// ============================================================
// Setup C: in-chunk triangle, fp32. tri[j][sl][cl] nonzero iff sl<cl && col<Mc.
// ============================================================
__global__ __launch_bounds__(NT)
void gather_tri_kernel(const float* __restrict__ w, const int* __restrict__ conn,
                       const int* __restrict__ hdr, const int* __restrict__ cmap,
                       float* __restrict__ tri) {
    const int Mc = hdr[0], nch = hdr[3];
    const int idx = blockIdx.x * NT + threadIdx.x;   // < 32*1024
    const int j  = idx >> 10;
    if (j >= nch) return;
    const int sl = (idx >> 5) & 31;
    const int cl = idx & 31;
    const int s = j * 32 + sl, c = j * 32 + cl;
    float v = 0.f;
    if (sl < cl && c < Mc) {
        const size_t o = (size_t)(IN_DIM + cmap[s]) * N_MID + cmap[c];
        v = w[o] * (float)conn[o];
    }
    tri[idx] = v;
}

// ============================================================
// Main kernel (net8): 256 blocks x 256 threads (4 waves), 64 rows/block.
// Mpad = TPW*64 (TPW even). One barrier per chunk.
// TPW==12: triple-buffer tri + bnx + phase-1 B dbuf (full features).
// TPW==14: double-buffer tri + bnx + phase-1 B dbuf.
// TPW==16: R9-equivalent minimal path (register ceiling).
// ============================================================
template <int TPW>
__global__ __launch_bounds__(256)
__attribute__((amdgpu_waves_per_eu(1, 1)))
void net8_kernel(const float* __restrict__ x,
                 const unsigned short* __restrict__ ew2,
                 const float* __restrict__ tri_g,
                 const int* __restrict__ hdr,
                 const int* __restrict__ ocol,
                 const float* __restrict__ biasc,
                 float* __restrict__ out) {
    if (hdr[1] != TPW * 64) return;
    constexpr int  TRN  = (TPW <= 12) ? 3 : 2;     // tri prefetch depth
    constexpr bool BNXF = (TPW <= 14);             // apply-B register prefetch
    constexpr bool P1DB = (TPW <= 14);             // phase-1 B double-buffer
    const int Mc  = hdr[0];
    const int tpm = TPW * 4;                       // Mpad/16
    const int nch = TPW * 2;                       // Mpad/32

    __shared__ __align__(16) unsigned short xa[4096 * 8];      // 65,536 B
    __shared__ __align__(16) float stage2[32 * 68];            //  8,704 B
    __shared__ __align__(16) unsigned short res2[2][2048];     //  8,192 B
    __shared__ __align__(16) float tri_lds[2][1024];           //  8,192 B
    __shared__ float bias_lds[1024];                           //  4,096 B
    __shared__ int   ocol_lds[1024];                           //  4,096 B

    const int t = threadIdx.x, lane = t & 63, w = t >> 6;  // w in 0..3
    const int l15 = lane & 15, q = lane >> 4;
    const int r0 = blockIdx.x * 64;
    const int g0 = w * TPW;

    // ---- stage bias/ocol ----
    for (int i = t; i < TPW * 64; i += 256) {
        bias_lds[i] = biasc[i];
        ocol_lds[i] = ocol[i];
    }
    // ---- tri chunk 0 (wave 3) ----
    if (w == 3) {
        const float4* src = (const float4*)tri_g;
#pragma unroll
        for (int u = 0; u < 4; ++u)
            *(float4*)&tri_lds[0][(lane + 64 * u) * 4] = src[lane + 64 * u];
    }
    // ---- x -> bf16 A-fragment-contiguous: frag i = (kb*4+rr)*64 + lane2 ----
    for (int i = t; i < 4096; i += 256) {
        const int lane2 = i & 63, rrkb = i >> 6;
        const int rr = rrkb & 3, kb = rrkb >> 2;
        const int qq = lane2 >> 4, ll = lane2 & 15;
        const int row = rr * 16 + ll;
        const int k0 = kb * 32 + qq * 8;
        const float4 f0 = *(const float4*)&x[(size_t)(r0 + row) * IN_DIM + k0];
        const float4 f1 = *(const float4*)&x[(size_t)(r0 + row) * IN_DIM + k0 + 4];
        unsigned short vv[8] = {f2bf(f0.x), f2bf(f0.y), f2bf(f0.z), f2bf(f0.w),
                                f2bf(f1.x), f2bf(f1.y), f2bf(f1.z), f2bf(f1.w)};
        *(uint4*)&xa[(size_t)i * 8] = *(uint4*)vv;
    }
    __syncthreads();

    ffrag acc[TPW][4];
#pragma unroll
    for (int tt = 0; tt < TPW; ++tt)
#pragma unroll
        for (int rr = 0; rr < 4; ++rr) acc[tt][rr] = (ffrag)0.f;

    // ---- phase 1: input GEMM, 16 k-steps ----
    if (P1DB) {
        bfrag b0[TPW], b1[TPW];
#pragma unroll
        for (int tt = 0; tt < TPW; ++tt)
            b0[tt] = *(const bfrag*)&ew2[((size_t)(0 * tpm + g0 + tt) * 64 + lane) * 8];
#pragma unroll 1
        for (int kb = 0; kb < 16; kb += 2) {
            if (kb + 1 < 16) {
#pragma unroll
                for (int tt = 0; tt < TPW; ++tt)
                    b1[tt] = *(const bfrag*)&ew2[((size_t)((kb + 1) * tpm + g0 + tt) * 64 + lane) * 8];
            }
            {
                bfrag a[4];
#pragma unroll
                for (int rr = 0; rr < 4; ++rr)
                    a[rr] = *(const bfrag*)&xa[((kb * 4 + rr) * 64 + lane) * 8];
#pragma unroll
                for (int tt = 0; tt < TPW; ++tt)
                    if ((g0 + tt) * 16 < Mc)
#pragma unroll
                        for (int rr = 0; rr < 4; ++rr)
                            acc[tt][rr] = __builtin_amdgcn_mfma_f32_16x16x32_bf16(a[rr], b0[tt], acc[tt][rr], 0, 0, 0);
            }
            if (kb + 2 < 16) {
#pragma unroll
                for (int tt = 0; tt < TPW; ++tt)
                    b0[tt] = *(const bfrag*)&ew2[((size_t)((kb + 2) * tpm + g0 + tt) * 64 + lane) * 8];
            }
            if (kb + 1 < 16) {
                bfrag a[4];
#pragma unroll
                for (int rr = 0; rr < 4; ++rr)
                    a[rr] = *(const bfrag*)&xa[(((kb + 1) * 4 + rr) * 64 + lane) * 8];
#pragma unroll
                for (int tt = 0; tt < TPW; ++tt)
                    if ((g0 + tt) * 16 < Mc)
#pragma unroll
                        for (int rr = 0; rr < 4; ++rr)
                            acc[tt][rr] = __builtin_amdgcn_mfma_f32_16x16x32_bf16(a[rr], b1[tt], acc[tt][rr], 0, 0, 0);
            }
        }
    } else {
#pragma unroll 1
        for (int kb = 0; kb < 16; ++kb) {
            bfrag a[4];
#pragma unroll
            for (int rr = 0; rr < 4; ++rr)
                a[rr] = *(const bfrag*)&xa[((kb * 4 + rr) * 64 + lane) * 8];
#pragma unroll
            for (int tt = 0; tt < TPW; ++tt) {
                if ((g0 + tt) * 16 < Mc) {
                    const bfrag b = *(const bfrag*)&ew2[((size_t)(kb * tpm + g0 + tt) * 64 + lane) * 8];
#pragma unroll
                    for (int rr = 0; rr < 4; ++rr)
                        acc[tt][rr] = __builtin_amdgcn_mfma_f32_16x16x32_bf16(a[rr], b, acc[tt][rr], 0, 0, 0);
                }
            }
        }
    }

    // ---- phase 2: sequential chunks, ONE barrier each ----
    bfrag bnx[BNXF ? TPW : 1];
#pragma unroll 1
    for (int j = 0; j < nch; ++j) {
        const int cbase = 32 * j;
        if (cbase >= Mc) break;                      // uniform

        if (j > 0) {                                 // apply res_{j-1}
            const int pr = (j - 1) & 1;
            bfrag a[4];
#pragma unroll
            for (int rr = 0; rr < 4; ++rr)
                a[rr] = *(const bfrag*)&res2[pr][(rr * 64 + lane) * 8];
            if (BNXF) {
#pragma unroll
                for (int tt = 0; tt < TPW; ++tt) {
                    const int col0 = (g0 + tt) * 16;
                    if (col0 >= cbase && col0 < Mc)
#pragma unroll
                        for (int rr = 0; rr < 4; ++rr)
                            acc[tt][rr] = __builtin_amdgcn_mfma_f32_16x16x32_bf16(a[rr], bnx[tt], acc[tt][rr], 0, 0, 0);
                }
            } else {
#pragma unroll
                for (int tt = 0; tt < TPW; ++tt) {
                    const int col0 = (g0 + tt) * 16;
                    if (col0 >= cbase && col0 < Mc) {
                        const bfrag b = *(const bfrag*)&ew2[((size_t)((15 + j) * tpm + g0 + tt) * 64 + lane) * 8];
#pragma unroll
                        for (int rr = 0; rr < 4; ++rr)
                            acc[tt][rr] = __builtin_amdgcn_mfma_f32_16x16x32_bf16(a[rr], b, acc[tt][rr], 0, 0, 0);
                    }
                }
            }
        }

        // prefetch apply-B for chunk j+1 (row 16+j) — latency hidden by resolve
        if (BNXF && (j + 1 < nch)) {
#pragma unroll
            for (int tt = 0; tt < TPW; ++tt)
                bnx[tt] = *(const bfrag*)&ew2[((size_t)((16 + j) * tpm + g0 + tt) * 64 + lane) * 8];
        }

        const int ow = (2 * j) / TPW;                // owner wave (tiles 2j, 2j+1)
        if (w == ow) {
            // ---- stage own chunk tiles: [col][row], b128 writes ----
#pragma unroll
            for (int tt = 0; tt < TPW; ++tt) {
                const int g = g0 + tt;
                if (g == 2 * j || g == 2 * j + 1) {
                    const int half = (g & 1) ? 16 : 0;
#pragma unroll
                    for (int rr = 0; rr < 4; ++rr)
                        *(ffrag*)&stage2[(half + l15) * 68 + rr * 16 + 4 * q] = acc[tt][rr];
                }
            }
            // ---- transposed resolve: lane = batch row ----
            const float* trij = tri_lds[j & 1];
            float reg[32];
#pragma unroll
            for (int c = 0; c < 32; ++c) reg[c] = stage2[c * 68 + lane];

            float4 tr[TRN][8];                       // tri row prefetch ring
#pragma unroll
            for (int p = 0; p < TRN - 1; ++p)
#pragma unroll
                for (int u = 0; u < 8; ++u)
                    tr[p][u] = *(const float4*)&trij[p * 32 + u * 4];

#pragma unroll
            for (int c = 0; c < 32; ++c) {
                if (c + TRN - 1 < 32) {
                    const int pin = (c + TRN - 1) % TRN;
#pragma unroll
                    for (int u = 0; u < 8; ++u)
                        tr[pin][u] = *(const float4*)&trij[(c + TRN - 1) * 32 + u * 4];
                }
                const int pc = c % TRN;
                const float s  = __fdividef(1.f, 1.f + __expf(-reg[c]));
                const float rs = s + bias_lds[cbase + c];
                reg[c] = rs;
#pragma unroll
                for (int k = c + 1; k < 32; ++k)
                    reg[k] = fmaf(rs, f4c(tr[pc][k >> 2], k & 3), reg[k]);
            }
            // ---- bulk res2 write: 4 x ds_write_b128 (A-frag layout, bf16) ----
            {
                unsigned short* resb = res2[j & 1];
                const int rowA = ((lane >> 4) * 64 + (lane & 15)) * 8;
#pragma unroll
                for (int qA = 0; qA < 4; ++qA) {
                    unsigned int u[4];
#pragma unroll
                    for (int i = 0; i < 4; ++i)
                        u[i] = (unsigned int)f2bf(reg[qA * 8 + 2 * i]) |
                               ((unsigned int)f2bf(reg[qA * 8 + 2 * i + 1]) << 16);
                    *(uint4*)&resb[rowA + qA * 128] = *(uint4*)u;
                }
            }
            // ---- bulk out stores ----
#pragma unroll
            for (int c = 0; c < 32; ++c) {
                const int oc = ocol_lds[cbase + c];  // uniform
                if (oc >= 0)
                    out[(size_t)(r0 + lane) * OUT_DIM + oc] = reg[c];
            }
        } else if (w == ((ow + 2) & 3)) {
            // prefetch tri for chunk j+1 (overlaps resolve)
            const int jn = j + 1;
            if (jn < nch && 32 * jn < Mc) {
                const float4* src = (const float4*)(tri_g + (size_t)jn * 1024);
#pragma unroll
                for (int u = 0; u < 4; ++u)
                    *(float4*)&tri_lds[jn & 1][(lane + 64 * u) * 4] = src[lane + 64 * u];
            }
        }
        __syncthreads();                             // the ONE barrier
    }
}

// ============================================================
// Fallback (Mc > 1024 or tiny ws): round-1 monolithic fp32 kernel.
// ============================================================
__global__ __launch_bounds__(NT, 4)
void net_v1_kernel(const float* __restrict__ x,
                   const float* __restrict__ wsrc,
                   const int* __restrict__ conn,
                   const float* __restrict__ bias,
                   const int* __restrict__ exist,
                   const int* __restrict__ hdr,   // null = always run
                   float* __restrict__ out) {
    if (hdr && hdr[1] <= 1024) return;
    __shared__ float xs[16 * XPAD];
    __shared__ float res_s[2][16];
    float* bias_s  = xs;
    float* exist_s = xs + N_MID;
    const int t = threadIdx.x, rg = t & 3, cg = t >> 2;
    const int r0 = blockIdx.x * 16;
    const int c0 = cg * 20;
    {
        const float4* xg = (const float4*)(x + (size_t)r0 * IN_DIM);
        for (int idx = t; idx < 16 * IN_DIM / 4; idx += NT) {
            const int r = idx >> 7, jj = idx & 127;
            *(float4*)&xs[r * XPAD + jj * 4] = xg[idx];
        }
    }
    __syncthreads();
    float acc[4][20];
#pragma unroll
    for (int a = 0; a < 4; ++a)
#pragma unroll
        for (int k = 0; k < 20; ++k) acc[a][k] = 0.f;
    for (int j = 0; j < IN_DIM; ++j) {
        const size_t woff = (size_t)j * N_MID + c0;
        const float xv0 = xs[rg * XPAD + j];
        const float xv1 = xs[(rg + 4) * XPAD + j];
        const float xv2 = xs[(rg + 8) * XPAD + j];
        const float xv3 = xs[(rg + 12) * XPAD + j];
#pragma unroll
        for (int qq = 0; qq < 5; ++qq) {
            float4 w4 = *(const float4*)(wsrc + woff + qq * 4);
            const int4 c4 = *(const int4*)(conn + woff + qq * 4);
            w4.x *= (float)c4.x; w4.y *= (float)c4.y;
            w4.z *= (float)c4.z; w4.w *= (float)c4.w;
            const float wq[4] = {w4.x, w4.y, w4.z, w4.w};
#pragma unroll
            for (int u = 0; u < 4; ++u) {
                const int k = qq * 4 + u;
                acc[0][k] = fmaf(xv0, wq[u], acc[0][k]);
                acc[1][k] = fmaf(xv1, wq[u], acc[1][k]);
                acc[2][k] = fmaf(xv2, wq[u], acc[2][k]);
                acc[3][k] = fmaf(xv3, wq[u], acc[3][k]);
            }
        }
    }
    __syncthreads();
    for (int idx = t; idx < N_MID; idx += NT) {
        bias_s[idx]  = bias[idx];
        exist_s[idx] = (float)exist[idx];
    }
    __syncthreads();
    int p = 0;
    for (int bb = 0; bb < 64; ++bb) {
#pragma unroll
        for (int kk = 0; kk < 20; ++kk) {
            const int i = bb * 20 + kk;
            const float e = exist_s[i];
            if (e != 0.f) {
                if (cg == bb) {
                    const float bv = bias_s[i];
#pragma unroll
                    for (int a = 0; a < 4; ++a) {
                        const float v = acc[a][kk];
                        const float s = __fdividef(1.f, 1.f + __expf(-v));
                        const float res = (s + bv) * e;
                        res_s[p][rg + 4 * a] = res;
                        if (i >= N_MID - OUT_DIM)
                            out[(size_t)(r0 + rg + 4 * a) * OUT_DIM + (i - (N_MID - OUT_DIM))] = res;
                    }
                }
                __syncthreads();
                const float rv0 = res_s[p][rg];
                const float rv1 = res_s[p][rg + 4];
                const float rv2 = res_s[p][rg + 8];
                const float rv3 = res_s[p][rg + 12];
                const size_t woff = (size_t)(IN_DIM + i) * N_MID + c0;
                if (cg > bb) {
#pragma unroll
                    for (int qq = 0; qq < 5; ++qq) {
                        float4 w4 = *(const float4*)(wsrc + woff + qq * 4);
                        const int4 c4 = *(const int4*)(conn + woff + qq * 4);
                        w4.x *= (float)c4.x; w4.y *= (float)c4.y;
                        w4.z *= (float)c4.z; w4.w *= (float)c4.w;
                        const float wq[4] = {w4.x, w4.y, w4.z, w4.w};
#pragma unroll
                        for (int u = 0; u < 4; ++u) {
                            const int k = qq * 4 + u;
                            acc[0][k] = fmaf(rv0, wq[u], acc[0][k]);
                            acc[1][k] = fmaf(rv1, wq[u], acc[1][k]);
                            acc[2][k] = fmaf(rv2, wq[u], acc[2][k]);
                            acc[3][k] = fmaf(rv3, wq[u], acc[3][k]);
                        }
                    }
                } else if (cg == bb) {
#pragma unroll
                    for (int k = kk + 1; k < 20; ++k) {
                        float ww = wsrc[woff + k] * (float)conn[woff + k];
                        acc[0][k] = fmaf(rv0, ww, acc[0][k]);
                        acc[1][k] = fmaf(rv1, ww, acc[1][k]);
                        acc[2][k] = fmaf(rv2, ww, acc[2][k]);
                        acc[3][k] = fmaf(rv3, ww, acc[3][k]);
                    }
                }
                p ^= 1;
            }
        }
    }
}

extern "C" void kernel_launch(void* const* d_in, const int* in_sizes, int n_in,
                              void* d_out, int out_size, void* d_ws, size_t ws_size,
                              hipStream_t stream) {
    const float* x      = (const float*)d_in[0];
    const float* weight = (const float*)d_in[1];
    const float* bias   = (const float*)d_in[2];
    const int*   conn   = (const int*)d_in[3];
    const int*   exist  = (const int*)d_in[4];
    float*       out    = (float*)d_out;

    if (ws_size >= WS_NEED) {
        char* ws = (char*)d_ws;
        unsigned short* ew2  = (unsigned short*)ws;
        float*          tri  = (float*)(ws + TRI_OFF);
        int*            hdr  = (int*)(ws + HDR_OFF);
        int*            cmap = (int*)(ws + CMAP_OFF);
        int*            ocolp= (int*)(ws + OCOL_OFF);
        float*          bsc  = (float*)(ws + BIASC_OFF);

        build_maps_kernel<<<1, 64, 0, stream>>>(exist, bias, hdr, cmap, ocolp, bsc);
        gather2c_kernel<<<192, NT, 0, stream>>>(weight, conn, hdr, cmap, ew2);
        gather_tri_kernel<<<128, NT, 0, stream>>>(weight, conn, hdr, cmap, tri);
        net8_kernel<12><<<256, 256, 0, stream>>>(x, ew2, tri, hdr, ocolp, bsc, out);
        net8_kernel<14><<<256, 256, 0, stream>>>(x, ew2, tri, hdr, ocolp, bsc, out);
        net8_kernel<16><<<256, 256, 0, stream>>>(x, ew2, tri, hdr, ocolp, bsc, out);
        net_v1_kernel<<<BATCH / 16, NT, 0, stream>>>(x, weight, conn, bias, exist, hdr, out);
    } else {
        net_v1_kernel<<<BATCH / 16, NT, 0, stream>>>(x, weight, conn, bias, exist, nullptr, out);
    }
}

// Round 11
// 362.601 us; speedup vs baseline: 1.1372x; 1.1372x over previous
//
#include <hip/hip_runtime.h>

#define IN_DIM   512
#define OUT_DIM  256
#define N_MID    1280
#define BATCH    16384
#define NT       256
#define XPAD     520      // fallback kernel x stride

// net9: 512 blocks x 256 threads (4 waves), 32 rows/block, 2 blocks/CU.
// R8/R9 lesson: 1 chain/CU leaves ~90% stall (25K cyc/chunk vs ~5K issue work).
// R10 lesson: extra prefetch arrays -> alloca promoted to LDS -> regression.
// R11: interleave 2 independent batch-chains per CU (LDS 58KB, 256-reg cap,
// acc[TPW][2]) with the proven R9 chain-lean resolver. Stalls of one chain
// are filled by the other chain's work.

// ---- workspace layout (max geometry: ksteps=48, tpm=64, nch=32) ----
#define EW2_ELEMS ((size_t)48 * 64 * 64 * 8)               // bf16 elems
#define EW2_BYTES (EW2_ELEMS * 2)                          // 3,145,728
#define TRI_OFF   EW2_BYTES
#define TRI_BYTES ((size_t)32 * 1024 * 4)                  // 131,072
#define HDR_OFF   (TRI_OFF + TRI_BYTES)
#define CMAP_OFF  (HDR_OFF + 32)
#define OCOL_OFF  (CMAP_OFF + N_MID * 4)
#define BIASC_OFF (OCOL_OFF + N_MID * 4)
#define WS_NEED   (BIASC_OFF + N_MID * 4)

typedef __attribute__((ext_vector_type(8))) short  bfrag;
typedef __attribute__((ext_vector_type(4))) float  ffrag;

__device__ __forceinline__ unsigned short f2bf(float f) {
    unsigned int u = __float_as_uint(f);
    u += 0x7FFFu + ((u >> 16) & 1u);       // RNE
    return (unsigned short)(u >> 16);
}

// static component select from float4 (constant-folded post-unroll)
__device__ __forceinline__ float f4c(const float4& v, int k) {
    return (k == 0) ? v.x : (k == 1) ? v.y : (k == 2) ? v.z : v.w;
}

// ============================================================
// Setup A: compact existing columns (1 wave).
// hdr = {Mc, Mpad, unused, nch=Mpad/32, tpm=Mpad/16}; Mpad in {768,896,1024}.
// ============================================================
__global__ void build_maps_kernel(const int* __restrict__ exist,
                                  const float* __restrict__ bias,
                                  int* __restrict__ hdr,
                                  int* __restrict__ cmap,
                                  int* __restrict__ ocol,
                                  float* __restrict__ biasc) {
    const int lane = threadIdx.x;   // 64
    int base = 0;
    for (int r = 0; r < N_MID / 64; ++r) {
        const int i = r * 64 + lane;
        const int e = exist[i];
        const unsigned long long m  = __ballot(e != 0);
        const unsigned long long lt = (lane == 0) ? 0ull : (~0ull >> (64 - lane));
        const int pos = base + __popcll(m & lt);
        if (e) {
            cmap[pos]  = i;
            ocol[pos]  = (i >= N_MID - OUT_DIM) ? (i - (N_MID - OUT_DIM)) : -1;
            biasc[pos] = bias[i];
        }
        base += __popcll(m);
    }
    for (int idx = base + lane; idx < N_MID; idx += 64) {
        cmap[idx] = 0; ocol[idx] = -1; biasc[idx] = 0.f;
    }
    if (lane == 0) {
        const int Mc = base;
        int Mpad;
        if (Mc <= 768) Mpad = 768;
        else if (Mc <= 896) Mpad = 896;
        else if (Mc <= 1024) Mpad = 1024;
        else Mpad = (Mc + 127) & ~127;     // v1 fallback territory
        hdr[0] = Mc; hdr[1] = Mpad; hdr[2] = 0;
        hdr[3] = Mpad / 32; hdr[4] = Mpad / 16;
    }
}

// ============================================================
// Setup B (coalesced, validated R10): eff_w -> bf16 B-fragment-major.
// ============================================================
__global__ __launch_bounds__(NT)
void gather2c_kernel(const float* __restrict__ w, const int* __restrict__ conn,
                     const int* __restrict__ hdr, const int* __restrict__ cmap,
                     unsigned short* __restrict__ ew2) {
    const int Mc = hdr[0], nch = hdr[3], tpm = hdr[4];
    if (tpm > 64) return;                          // v1 fallback case
    const int kstep = blockIdx.x >> 2;
    const int q8    = blockIdx.x & 3;
    if (kstep >= 16 + nch) return;

    __shared__ float rb[8][N_MID];                 // 40,960 B
    const int t = threadIdx.x;

    for (int idx = t; idx < 8 * (N_MID / 4); idx += NT) {
        const int j  = idx / (N_MID / 4);
        const int c4 = idx % (N_MID / 4);
        int sr = -1;
        if (kstep < 16) {
            sr = kstep * 32 + q8 * 8 + j;
        } else {
            const int s2 = (kstep - 16) * 32 + q8 * 8 + j;
            if (s2 < Mc) sr = IN_DIM + cmap[s2];
        }
        float4 v = make_float4(0.f, 0.f, 0.f, 0.f);
        if (sr >= 0) {
            const size_t o = (size_t)sr * N_MID + c4 * 4;
            v = *(const float4*)(w + o);
            const int4 cc = *(const int4*)(conn + o);
            v.x *= (float)cc.x; v.y *= (float)cc.y;
            v.z *= (float)cc.z; v.w *= (float)cc.w;
        }
        *(float4*)&rb[j][c4 * 4] = v;
    }
    __syncthreads();

    for (int i = t; i < tpm * 16; i += NT) {
        const int gt = i >> 4, l15 = i & 15;
        const int c  = gt * 16 + l15;
        const int cm = (c < Mc) ? cmap[c] : 0;
        unsigned short vv[8];
#pragma unroll
        for (int jj = 0; jj < 8; ++jj) {
            float v = 0.f;
            if (c < Mc) {
                if (kstep < 16) {
                    v = rb[jj][cm];
                } else {
                    const int s2 = (kstep - 16) * 32 + q8 * 8 + jj;
                    if (s2 < c && (s2 >> 5) != (c >> 5))
                        v = rb[jj][cm];
                }
            }
            vv[jj] = f2bf(v);
        }
        *(uint4*)&ew2[((size_t)(kstep * tpm + gt) * 64 + (q8 * 16 + l15)) * 8] = *(uint4*)vv;
    }
}

// ============================================================
// Setup C: in-chunk triangle, fp32. tri[j][sl][cl] nonzero iff sl<cl && col<Mc.
// ============================================================
__global__ __launch_bounds__(NT)
void gather_tri_kernel(const float* __restrict__ w, const int* __restrict__ conn,
                       const int* __restrict__ hdr, const int* __restrict__ cmap,
                       float* __restrict__ tri) {
    const int Mc = hdr[0], nch = hdr[3];
    const int idx = blockIdx.x * NT + threadIdx.x;   // < 32*1024
    const int j  = idx >> 10;
    if (j >= nch) return;
    const int sl = (idx >> 5) & 31;
    const int cl = idx & 31;
    const int s = j * 32 + sl, c = j * 32 + cl;
    float v = 0.f;
    if (sl < cl && c < Mc) {
        const size_t o = (size_t)(IN_DIM + cmap[s]) * N_MID + cmap[c];
        v = w[o] * (float)conn[o];
    }
    tri[idx] = v;
}

// ============================================================
// Main kernel (net9): 512 blocks x 256 threads (4 waves), 32 rows/block,
// 2 blocks/CU. Mpad = TPW*64 (TPW even). One barrier per chunk.
// acc[TPW][2] (2 row-groups of 16). R9 chain-lean resolver, lanes<32 active.
// ============================================================
template <int TPW>
__global__ __launch_bounds__(256)
__attribute__((amdgpu_waves_per_eu(2, 2)))
void net9_kernel(const float* __restrict__ x,
                 const unsigned short* __restrict__ ew2,
                 const float* __restrict__ tri_g,
                 const int* __restrict__ hdr,
                 const int* __restrict__ ocol,
                 const float* __restrict__ biasc,
                 float* __restrict__ out) {
    if (hdr[1] != TPW * 64) return;
    const int Mc  = hdr[0];
    const int tpm = TPW * 4;                       // Mpad/16
    const int nch = TPW * 2;                       // Mpad/32

    __shared__ __align__(16) unsigned short xa[2048 * 8];      // 32,768 B
    __shared__ __align__(16) float stage2[32 * 36 + 64];       //  4,864 B ([col][row], stride 36)
    __shared__ __align__(16) unsigned short res2[2][1024];     //  4,096 B
    __shared__ __align__(16) float tri_lds[2][1024];           //  8,192 B
    __shared__ float bias_lds[1024];                           //  4,096 B
    __shared__ int   ocol_lds[1024];                           //  4,096 B
    // total ~58.1 KB -> 2 blocks/CU; 8 waves/CU -> 2 waves/SIMD -> 256-reg cap

    const int t = threadIdx.x, lane = t & 63, w = t >> 6;  // w in 0..3
    const int l15 = lane & 15, q = lane >> 4;
    const int r0 = blockIdx.x * 32;
    const int g0 = w * TPW;

    // ---- stage bias/ocol ----
    for (int i = t; i < TPW * 64; i += 256) {
        bias_lds[i] = biasc[i];
        ocol_lds[i] = ocol[i];
    }
    // ---- tri chunk 0 (wave 3) ----
    if (w == 3) {
        const float4* src = (const float4*)tri_g;
#pragma unroll
        for (int u = 0; u < 4; ++u)
            *(float4*)&tri_lds[0][(lane + 64 * u) * 4] = src[lane + 64 * u];
    }
    // ---- x -> bf16 A-frag-contiguous: frag i = (kb*2+rr)*64 + lane2 ----
    for (int i = t; i < 2048; i += 256) {
        const int lane2 = i & 63, rrkb = i >> 6;   // rrkb in 0..31
        const int rr = rrkb & 1, kb = rrkb >> 1;
        const int qq = lane2 >> 4, ll = lane2 & 15;
        const int row = rr * 16 + ll;
        const int k0 = kb * 32 + qq * 8;
        const float4 f0 = *(const float4*)&x[(size_t)(r0 + row) * IN_DIM + k0];
        const float4 f1 = *(const float4*)&x[(size_t)(r0 + row) * IN_DIM + k0 + 4];
        unsigned short vv[8] = {f2bf(f0.x), f2bf(f0.y), f2bf(f0.z), f2bf(f0.w),
                                f2bf(f1.x), f2bf(f1.y), f2bf(f1.z), f2bf(f1.w)};
        *(uint4*)&xa[(size_t)i * 8] = *(uint4*)vv;
    }
    __syncthreads();

    ffrag acc[TPW][2];
#pragma unroll
    for (int tt = 0; tt < TPW; ++tt)
#pragma unroll
        for (int rr = 0; rr < 2; ++rr) acc[tt][rr] = (ffrag)0.f;

    // ---- phase 1: input GEMM, 16 k-steps ----
#pragma unroll 1
    for (int kb = 0; kb < 16; ++kb) {
        bfrag a[2];
#pragma unroll
        for (int rr = 0; rr < 2; ++rr)
            a[rr] = *(const bfrag*)&xa[((kb * 2 + rr) * 64 + lane) * 8];
#pragma unroll
        for (int tt = 0; tt < TPW; ++tt) {
            if ((g0 + tt) * 16 < Mc) {
                const bfrag b = *(const bfrag*)&ew2[((size_t)(kb * tpm + g0 + tt) * 64 + lane) * 8];
#pragma unroll
                for (int rr = 0; rr < 2; ++rr)
                    acc[tt][rr] = __builtin_amdgcn_mfma_f32_16x16x32_bf16(a[rr], b, acc[tt][rr], 0, 0, 0);
            }
        }
    }

    // ---- phase 2: sequential chunks, ONE barrier each ----
#pragma unroll 1
    for (int j = 0; j < nch; ++j) {
        const int cbase = 32 * j;
        if (cbase >= Mc) break;                      // uniform

        if (j > 0) {                                 // apply res_{j-1}
            const int pr = (j - 1) & 1;
            bfrag a[2];
#pragma unroll
            for (int rr = 0; rr < 2; ++rr)
                a[rr] = *(const bfrag*)&res2[pr][(rr * 64 + lane) * 8];
#pragma unroll
            for (int tt = 0; tt < TPW; ++tt) {
                const int col0 = (g0 + tt) * 16;
                if (col0 >= cbase && col0 < Mc) {
                    const bfrag b = *(const bfrag*)&ew2[((size_t)((15 + j) * tpm + g0 + tt) * 64 + lane) * 8];
#pragma unroll
                    for (int rr = 0; rr < 2; ++rr)
                        acc[tt][rr] = __builtin_amdgcn_mfma_f32_16x16x32_bf16(a[rr], b, acc[tt][rr], 0, 0, 0);
                }
            }
        }

        const int ow = (2 * j) / TPW;                // owner wave (tiles 2j, 2j+1)
        if (w == ow) {
            // ---- stage own chunk tiles: [col][row] (stride 36), b128 writes ----
#pragma unroll
            for (int tt = 0; tt < TPW; ++tt) {
                const int g = g0 + tt;
                if (g == 2 * j || g == 2 * j + 1) {
                    const int half = (g & 1) ? 16 : 0;
#pragma unroll
                    for (int rr = 0; rr < 2; ++rr)
                        *(ffrag*)&stage2[(half + l15) * 36 + rr * 16 + 4 * q] = acc[tt][rr];
                }
            }
            // ---- transposed resolve: lane = batch row (lanes 0..31 live) ----
            const float* trij = tri_lds[j & 1];
            float reg[32];
#pragma unroll
            for (int c = 0; c < 32; ++c) reg[c] = stage2[c * 36 + (lane & 31)];

            float4 tr[2][8];                         // tri row double-buffer
#pragma unroll
            for (int u = 0; u < 8; ++u) tr[0][u] = *(const float4*)&trij[u * 4];

#pragma unroll
            for (int c = 0; c < 32; ++c) {
                const int cb = c & 1;
                if (c < 31) {
#pragma unroll
                    for (int u = 0; u < 8; ++u)
                        tr[cb ^ 1][u] = *(const float4*)&trij[(c + 1) * 32 + u * 4];
                }
                const float s  = __fdividef(1.f, 1.f + __expf(-reg[c]));
                const float rs = s + bias_lds[cbase + c];
                reg[c] = rs;
#pragma unroll
                for (int k = c + 1; k < 32; ++k)
                    reg[k] = fmaf(rs, f4c(tr[cb][k >> 2], k & 3), reg[k]);
            }
            // ---- bulk res2 write (A-frag layout, bf16), lanes 0..31 ----
            if (lane < 32) {
                unsigned short* resb = res2[j & 1];
                const int rowA = ((lane >> 4) * 64 + (lane & 15)) * 8;
#pragma unroll
                for (int qA = 0; qA < 4; ++qA) {
                    unsigned int u[4];
#pragma unroll
                    for (int i = 0; i < 4; ++i)
                        u[i] = (unsigned int)f2bf(reg[qA * 8 + 2 * i]) |
                               ((unsigned int)f2bf(reg[qA * 8 + 2 * i + 1]) << 16);
                    *(uint4*)&resb[rowA + qA * 128] = *(uint4*)u;
                }
                // ---- bulk out stores ----
#pragma unroll
                for (int c = 0; c < 32; ++c) {
                    const int oc = ocol_lds[cbase + c];  // uniform
                    if (oc >= 0)
                        out[(size_t)(r0 + lane) * OUT_DIM + oc] = reg[c];
                }
            }
        } else if (w == ((ow + 2) & 3)) {
            // prefetch tri for chunk j+1 (overlaps resolve)
            const int jn = j + 1;
            if (jn < nch && 32 * jn < Mc) {
                const float4* src = (const float4*)(tri_g + (size_t)jn * 1024);
#pragma unroll
                for (int u = 0; u < 4; ++u)
                    *(float4*)&tri_lds[jn & 1][(lane + 64 * u) * 4] = src[lane + 64 * u];
            }
        }
        __syncthreads();                             // the ONE barrier
    }
}

// ============================================================
// Fallback (Mc > 1024 or tiny ws): round-1 monolithic fp32 kernel.
// ============================================================
__global__ __launch_bounds__(NT, 4)
void net_v1_kernel(const float* __restrict__ x,
                   const float* __restrict__ wsrc,
                   const int* __restrict__ conn,
                   const float* __restrict__ bias,
                   const int* __restrict__ exist,
                   const int* __restrict__ hdr,   // null = always run
                   float* __restrict__ out) {
    if (hdr && hdr[1] <= 1024) return;
    __shared__ float xs[16 * XPAD];
    __shared__ float res_s[2][16];
    float* bias_s  = xs;
    float* exist_s = xs + N_MID;
    const int t = threadIdx.x, rg = t & 3, cg = t >> 2;
    const int r0 = blockIdx.x * 16;
    const int c0 = cg * 20;
    {
        const float4* xg = (const float4*)(x + (size_t)r0 * IN_DIM);
        for (int idx = t; idx < 16 * IN_DIM / 4; idx += NT) {
            const int r = idx >> 7, jj = idx & 127;
            *(float4*)&xs[r * XPAD + jj * 4] = xg[idx];
        }
    }
    __syncthreads();
    float acc[4][20];
#pragma unroll
    for (int a = 0; a < 4; ++a)
#pragma unroll
        for (int k = 0; k < 20; ++k) acc[a][k] = 0.f;
    for (int j = 0; j < IN_DIM; ++j) {
        const size_t woff = (size_t)j * N_MID + c0;
        const float xv0 = xs[rg * XPAD + j];
        const float xv1 = xs[(rg + 4) * XPAD + j];
        const float xv2 = xs[(rg + 8) * XPAD + j];
        const float xv3 = xs[(rg + 12) * XPAD + j];
#pragma unroll
        for (int qq = 0; qq < 5; ++qq) {
            float4 w4 = *(const float4*)(wsrc + woff + qq * 4);
            const int4 c4 = *(const int4*)(conn + woff + qq * 4);
            w4.x *= (float)c4.x; w4.y *= (float)c4.y;
            w4.z *= (float)c4.z; w4.w *= (float)c4.w;
            const float wq[4] = {w4.x, w4.y, w4.z, w4.w};
#pragma unroll
            for (int u = 0; u < 4; ++u) {
                const int k = qq * 4 + u;
                acc[0][k] = fmaf(xv0, wq[u], acc[0][k]);
                acc[1][k] = fmaf(xv1, wq[u], acc[1][k]);
                acc[2][k] = fmaf(xv2, wq[u], acc[2][k]);
                acc[3][k] = fmaf(xv3, wq[u], acc[3][k]);
            }
        }
    }
    __syncthreads();
    for (int idx = t; idx < N_MID; idx += NT) {
        bias_s[idx]  = bias[idx];
        exist_s[idx] = (float)exist[idx];
    }
    __syncthreads();
    int p = 0;
    for (int bb = 0; bb < 64; ++bb) {
#pragma unroll
        for (int kk = 0; kk < 20; ++kk) {
            const int i = bb * 20 + kk;
            const float e = exist_s[i];
            if (e != 0.f) {
                if (cg == bb) {
                    const float bv = bias_s[i];
#pragma unroll
                    for (int a = 0; a < 4; ++a) {
                        const float v = acc[a][kk];
                        const float s = __fdividef(1.f, 1.f + __expf(-v));
                        const float res = (s + bv) * e;
                        res_s[p][rg + 4 * a] = res;
                        if (i >= N_MID - OUT_DIM)
                            out[(size_t)(r0 + rg + 4 * a) * OUT_DIM + (i - (N_MID - OUT_DIM))] = res;
                    }
                }
                __syncthreads();
                const float rv0 = res_s[p][rg];
                const float rv1 = res_s[p][rg + 4];
                const float rv2 = res_s[p][rg + 8];
                const float rv3 = res_s[p][rg + 12];
                const size_t woff = (size_t)(IN_DIM + i) * N_MID + c0;
                if (cg > bb) {
#pragma unroll
                    for (int qq = 0; qq < 5; ++qq) {
                        float4 w4 = *(const float4*)(wsrc + woff + qq * 4);
                        const int4 c4 = *(const int4*)(conn + woff + qq * 4);
                        w4.x *= (float)c4.x; w4.y *= (float)c4.y;
                        w4.z *= (float)c4.z; w4.w *= (float)c4.w;
                        const float wq[4] = {w4.x, w4.y, w4.z, w4.w};
#pragma unroll
                        for (int u = 0; u < 4; ++u) {
                            const int k = qq * 4 + u;
                            acc[0][k] = fmaf(rv0, wq[u], acc[0][k]);
                            acc[1][k] = fmaf(rv1, wq[u], acc[1][k]);
                            acc[2][k] = fmaf(rv2, wq[u], acc[2][k]);
                            acc[3][k] = fmaf(rv3, wq[u], acc[3][k]);
                        }
                    }
                } else if (cg == bb) {
#pragma unroll
                    for (int k = kk + 1; k < 20; ++k) {
                        float ww = wsrc[woff + k] * (float)conn[woff + k];
                        acc[0][k] = fmaf(rv0, ww, acc[0][k]);
                        acc[1][k] = fmaf(rv1, ww, acc[1][k]);
                        acc[2][k] = fmaf(rv2, ww, acc[2][k]);
                        acc[3][k] = fmaf(rv3, ww, acc[3][k]);
                    }
                }
                p ^= 1;
            }
        }
    }
}

extern "C" void kernel_launch(void* const* d_in, const int* in_sizes, int n_in,
                              void* d_out, int out_size, void* d_ws, size_t ws_size,
                              hipStream_t stream) {
    const float* x      = (const float*)d_in[0];
    const float* weight = (const float*)d_in[1];
    const float* bias   = (const float*)d_in[2];
    const int*   conn   = (const int*)d_in[3];
    const int*   exist  = (const int*)d_in[4];
    float*       out    = (float*)d_out;

    if (ws_size >= WS_NEED) {
        char* ws = (char*)d_ws;
        unsigned short* ew2  = (unsigned short*)ws;
        float*          tri  = (float*)(ws + TRI_OFF);
        int*            hdr  = (int*)(ws + HDR_OFF);
        int*            cmap = (int*)(ws + CMAP_OFF);
        int*            ocolp= (int*)(ws + OCOL_OFF);
        float*          bsc  = (float*)(ws + BIASC_OFF);

        build_maps_kernel<<<1, 64, 0, stream>>>(exist, bias, hdr, cmap, ocolp, bsc);
        gather2c_kernel<<<192, NT, 0, stream>>>(weight, conn, hdr, cmap, ew2);
        gather_tri_kernel<<<128, NT, 0, stream>>>(weight, conn, hdr, cmap, tri);
        net9_kernel<12><<<512, 256, 0, stream>>>(x, ew2, tri, hdr, ocolp, bsc, out);
        net9_kernel<14><<<512, 256, 0, stream>>>(x, ew2, tri, hdr, ocolp, bsc, out);
        net9_kernel<16><<<512, 256, 0, stream>>>(x, ew2, tri, hdr, ocolp, bsc, out);
        net_v1_kernel<<<BATCH / 16, NT, 0, stream>>>(x, weight, conn, bias, exist, hdr, out);
    } else {
        net_v1_kernel<<<BATCH / 16, NT, 0, stream>>>(x, weight, conn, bias, exist, nullptr, out);
    }
}